// Round 10
// baseline (1543.934 us; speedup 1.0000x reference)
//
#include <hip/hip_runtime.h>

// LSTMBaseline: B=2048, T=512, H=128, 4H=512, FF=64, OUT=2 ; fp32 in/out.
// R10: transpose-free cell. Trick: batch=8 uses only rows 0-7 of the M=16
// MFMA; rows 8-15 output lands in lanes kg>=2 which were idle in cell math.
//  - h0 stored DUPLICATED at rows {r, r+8} of its buffer -> D0 rows 0-7 =
//    gates0 (lanes kg<2); D1 = [h0;h1]@W1 with h1 stored at rows 8-15
//    (rows 0-7 zero) -> D1 rows 8-15 = gates1 (lanes kg>=2).
//  - Cell: every lane owns 4 units in-register (cndmask acc0/acc1, per-lane
//    bias / wih0 consts, zero for layer-1 lanes). NO gates LDS round-trip.
//  - ONE barrier and ONE LDS drain per timestep.
// Weights as bf16 B-frags pinned to AGPRs (R8). 256 blocks x 512 threads.

#define TT 512
#define HH 128
#define FFD 64
#define BB 8
#define NT 512   // 8 waves
#define HP 136   // padded LDS row stride (ushort)
#define XP (TT + 2)

typedef __attribute__((ext_vector_type(8))) short short8;
typedef __attribute__((ext_vector_type(4))) float f32x4;

__device__ __forceinline__ unsigned short f2b(float f) {
    unsigned int i = __builtin_bit_cast(unsigned int, f);
    i += 0x7FFFu + ((i >> 16) & 1u);   // RNE
    return (unsigned short)(i >> 16);
}
__device__ __forceinline__ float b2f(unsigned short u) {
    return __builtin_bit_cast(float, ((unsigned int)u) << 16);
}
__device__ __forceinline__ float fexp2(float x) {
#if __has_builtin(__builtin_amdgcn_exp2f)
    return __builtin_amdgcn_exp2f(x);
#else
    float r; asm volatile("v_exp_f32 %0, %1" : "=v"(r) : "v"(x)); return r;
#endif
}
__device__ __forceinline__ float frcp(float x) {
#if __has_builtin(__builtin_amdgcn_rcpf)
    return __builtin_amdgcn_rcpf(x);
#else
    float r; asm volatile("v_rcp_f32 %0, %1" : "=v"(r) : "v"(x)); return r;
#endif
}
__device__ __forceinline__ float sigm(float x) {
    return frcp(1.0f + fexp2(-1.4426950408889634f * x));
}
__device__ __forceinline__ float tanh_f(float x) {
    return 1.0f - 2.0f * frcp(1.0f + fexp2(2.8853900817779268f * x));
}
__device__ __forceinline__ short8 ldfrag(const float* p, unsigned idx) {
    const float4* q = reinterpret_cast<const float4*>(p + idx);
    float4 a = q[0], b = q[1];
    short8 s;
    s[0] = (short)f2b(a.x); s[1] = (short)f2b(a.y);
    s[2] = (short)f2b(a.z); s[3] = (short)f2b(a.w);
    s[4] = (short)f2b(b.x); s[5] = (short)f2b(b.y);
    s[6] = (short)f2b(b.z); s[7] = (short)f2b(b.w);
    return s;
}

__global__ __launch_bounds__(NT, 1) void lstm2_fused(
    const float* __restrict__ hr,
    const float* __restrict__ glu,
    const float* __restrict__ wih0,
    const float* __restrict__ whh0,
    const float* __restrict__ bih0,
    const float* __restrict__ bhh0,
    const float* __restrict__ wih1,
    const float* __restrict__ whh1,
    const float* __restrict__ bih1,
    const float* __restrict__ bhh1,
    const float* __restrict__ w1,
    const float* __restrict__ b1,
    const float* __restrict__ w2,
    const float* __restrict__ b2,
    float* __restrict__ out)
{
    // hb[layer][parity][16][HP]; layer0: h0 dup rows {r,r+8}; layer1: h1 at
    // rows 8-15, rows 0-7 stay zero forever.
    __shared__ __align__(16) unsigned short hb[2 * 2 * 16 * HP];
    __shared__ float xin[BB][XP][2];      // (hr, glu) interleaved
    __shared__ float hid[BB][FFD];

    const int tid  = threadIdx.x;
    const int lane = tid & 63;
    const int wv   = tid >> 6;        // 0..7
    const int nrow = lane & 15;       // MFMA row (A) / col (B/D) index
    const int kg   = lane >> 4;       // 0..3
    const bool is0 = (kg < 2);        // layer-0 cell lane?
    const int b0   = blockIdx.x * BB;

    // ---- init LDS ----
    for (int i = tid; i < 2 * 2 * 16 * HP; i += NT) hb[i] = 0;
    for (int i = tid; i < BB * TT; i += NT) {
        int row = i >> 9;
        int t   = i & (TT - 1);
        unsigned gi = (unsigned)(b0 + row) * TT + t;
        xin[row][t][0] = hr[gi];
        xin[row][t][1] = glu[gi];
    }

    // ---- weight fragments: wave wv owns gate cols {128g + 16wv + nrow} ----
    short8 W0f[4][4];   // whh0, K=128
    short8 W1f[4][8];   // wih1 (kt<4) / whh1 (kt>=4), K=256
#pragma unroll
    for (int g = 0; g < 4; g++) {
        unsigned gc = (unsigned)(128 * g + 16 * wv + nrow);
#pragma unroll
        for (int kt = 0; kt < 4; kt++) {
            unsigned off = gc * HH + kt * 32 + kg * 8;
            W0f[g][kt]     = ldfrag(whh0, off);
            W1f[g][kt]     = ldfrag(wih1, off);
            W1f[g][kt + 4] = ldfrag(whh1, off);
        }
    }
#pragma unroll
    for (int g = 0; g < 4; g++) {
#pragma unroll
        for (int kt = 0; kt < 4; kt++) { asm volatile("" : "+a"(W0f[g][kt])); }
#pragma unroll
        for (int kt = 0; kt < 8; kt++) { asm volatile("" : "+a"(W1f[g][kt])); }
    }

    // ---- per-lane cell constants ----
    const int j    = 16 * wv + nrow;                 // hidden column
    const int rbx  = is0 ? 4 * kg : 4 * (kg - 2);    // batch-row base 0 or 4
    const int rowb = is0 ? 4 * kg : 8 + 4 * (kg - 2);// write-row base in hb
    const unsigned wconst = (is0 ? 0u : 1u) * (2 * 16 * HP) + (unsigned)rowb * HP + j;
    const unsigned dupoff = is0 ? 8u * HP : 0u;      // h0 dup row (+8); h1: rewrite
    float bg[4], wag[4], wbg[4];
#pragma unroll
    for (int g = 0; g < 4; g++) {
        int col = 128 * g + j;
        bg[g]  = is0 ? (bih0[col] + bhh0[col]) : (bih1[col] + bhh1[col]);
        wag[g] = is0 ? wih0[2 * col]     : 0.f;
        wbg[g] = is0 ? wih0[2 * col + 1] : 0.f;
    }
    const float g1keep = is0 ? 1.f : 0.f;
    float cst[4] = {0.f, 0.f, 0.f, 0.f};
    __syncthreads();

    // ---- recurrence: one barrier, one LDS drain per iteration ----
    for (int it = 0; it <= TT; it++) {
        const int p = (it + 1) & 1;    // parity holding h0(it-1) / writes h1(it-1)
        const int q = it & 1;          // parity holding h1(it-2) / writes h0(it)

        const unsigned short* A0 = &hb[(0 * 2 + p) * 16 * HP + nrow * HP];
        const unsigned short* A1 = &hb[(1 * 2 + q) * 16 * HP + nrow * HP];
        short8 a0[4], a1[4];
#pragma unroll
        for (int kt = 0; kt < 4; kt++) {
            a0[kt] = *reinterpret_cast<const short8*>(A0 + kt * 32 + kg * 8);
            a1[kt] = *reinterpret_cast<const short8*>(A1 + kt * 32 + kg * 8);
        }

        f32x4 acc0[4], acc1[4];
#pragma unroll
        for (int g = 0; g < 4; g++) { f32x4 z = {0.f, 0.f, 0.f, 0.f}; acc0[g] = z; acc1[g] = z; }
#pragma unroll
        for (int kt = 0; kt < 4; kt++)
#pragma unroll
            for (int g = 0; g < 4; g++)
                acc0[g] = __builtin_amdgcn_mfma_f32_16x16x32_bf16(a0[kt], W0f[g][kt], acc0[g], 0, 0, 0);
#pragma unroll
        for (int kt = 0; kt < 4; kt++)
#pragma unroll
            for (int g = 0; g < 4; g++)
                acc1[g] = __builtin_amdgcn_mfma_f32_16x16x32_bf16(a0[kt], W1f[g][kt], acc1[g], 0, 0, 0);
#pragma unroll
        for (int kt = 0; kt < 4; kt++)
#pragma unroll
            for (int g = 0; g < 4; g++)
                acc1[g] = __builtin_amdgcn_mfma_f32_16x16x32_bf16(a1[kt], W1f[g][kt + 4], acc1[g], 0, 0, 0);

        // lanes kg<2: acc0 rows 0-7 = gates0(it); kg>=2: acc1 rows 8-15 = gates1(it-1)
        const float keep = (it == 0) ? g1keep : 1.0f;
        const unsigned parw = (unsigned)(is0 ? q : p);
        unsigned short* wptr = &hb[wconst + parw * (16 * HP)];
#pragma unroll
        for (int rr = 0; rr < 4; rr++) {
            int ri = rbx + rr;
            float xh = xin[ri][it][0];
            float xg = xin[ri][it][1];
            float p0 = (is0 ? acc0[0][rr] : acc1[0][rr]) + bg[0] + xh * wag[0] + xg * wbg[0];
            float p1 = (is0 ? acc0[1][rr] : acc1[1][rr]) + bg[1] + xh * wag[1] + xg * wbg[1];
            float p2 = (is0 ? acc0[2][rr] : acc1[2][rr]) + bg[2] + xh * wag[2] + xg * wbg[2];
            float p3 = (is0 ? acc0[3][rr] : acc1[3][rr]) + bg[3] + xh * wag[3] + xg * wbg[3];
            float ig = sigm(p0), fg = sigm(p1), gg = tanh_f(p2), og = sigm(p3);
            float c = (fg * cst[rr] + ig * gg) * keep;
            cst[rr] = c;
            unsigned short hv = f2b(og * tanh_f(c));
            wptr[rr * HP]          = hv;   // h0 row r (kg<2) / h1 row 8+r (kg>=2)
            wptr[rr * HP + dupoff] = hv;   // h0 dup row r+8 / h1 same-addr rewrite
        }
        __syncthreads();
    }

    // ---- head: h1(TT-1) lives in hb[1][1] rows 8-15 ----
    {
        int r  = tid >> 6;      // 0..7
        int ff = tid & 63;
        const unsigned short* h1f = &hb[(1 * 2 + 1) * 16 * HP + (8 + r) * HP];
        float a2 = 0.f;
        for (int k = 0; k < HH; k++)
            a2 += b2f(h1f[k]) * w1[(unsigned)ff * HH + k];
        hid[r][ff] = fmaxf(a2 + b1[ff], 0.f);
    }
    __syncthreads();
    if (tid < 16) {
        int r = tid >> 1;
        int o = tid & 1;
        float a2 = b2[o];
        for (int k = 0; k < FFD; k++)
            a2 += hid[r][k] * w2[(unsigned)o * FFD + k];
        out[(b0 + r) * 2 + o] = a2;    // fp32 output
    }
}

extern "C" void kernel_launch(void* const* d_in, const int* in_sizes, int n_in,
                              void* d_out, int out_size, void* d_ws, size_t ws_size,
                              hipStream_t stream) {
    const float* hr   = (const float*)d_in[0];
    const float* glu  = (const float*)d_in[1];
    const float* wih0 = (const float*)d_in[2];
    const float* whh0 = (const float*)d_in[3];
    const float* bih0 = (const float*)d_in[4];
    const float* bhh0 = (const float*)d_in[5];
    const float* wih1 = (const float*)d_in[6];
    const float* whh1 = (const float*)d_in[7];
    const float* bih1 = (const float*)d_in[8];
    const float* bhh1 = (const float*)d_in[9];
    const float* w1   = (const float*)d_in[10];
    const float* b1   = (const float*)d_in[11];
    const float* w2   = (const float*)d_in[12];
    const float* b2   = (const float*)d_in[13];
    float* out = (float*)d_out;

    lstm2_fused<<<dim3(2048 / BB), dim3(NT), 0, stream>>>(
        hr, glu, wih0, whh0, bih0, bhh0, wih1, whh1, bih1, bhh1,
        w1, b1, w2, b2, out);
}

// Round 14
// 1431.702 us; speedup vs baseline: 1.0784x; 1.0784x over previous
//
#include <hip/hip_runtime.h>

// LSTMBaseline: B=2048, T=512, H=128, 4H=512, FF=64, OUT=2 ; fp32 in/out.
// R14 = R9 core (verified) + R10's dup-row gate delivery (verified), with
// register-pressure discipline. Transposed-MFMA line (R11-13) abandoned.
//  - h0 stored rows 0-7 AND duplicated rows 8-15; h1 stored rows 8-15
//    (rows 0-7 stay zero). MM0: D rows 0-7 = gates0 -> lanes kg<2.
//    MM1 (A=[h0dup;h1]): D rows 8-15 = gates1 -> lanes kg>=2.
//  - Every lane runs exactly 4 cell units branchlessly (16 cndmask selects,
//    keep-trick bootstrap). NO gates LDS round-trip, ONE barrier/iter.
//  - Anti-spill (R10's failure): a-frags streamed one-at-a-time (8 live regs
//    vs 32); 12 loop-invariant cell constants hoisted to registers; weights
//    (192 regs) AGPR-pinned.
// Wave wv owns gate cols {128g + 16wv + nrow}, g=0..3 (R9 layout).

#define TT 512
#define HH 128
#define GG 512
#define FFD 64
#define BB 8
#define NT 512   // 8 waves
#define HP 136   // padded LDS row stride (ushort); 272B, 16B-aligned rows

typedef __attribute__((ext_vector_type(8))) short short8;
typedef __attribute__((ext_vector_type(4))) float f32x4;

__device__ __forceinline__ unsigned short f2b(float f) {
    unsigned int i = __builtin_bit_cast(unsigned int, f);
    i += 0x7FFFu + ((i >> 16) & 1u);   // RNE
    return (unsigned short)(i >> 16);
}
__device__ __forceinline__ float b2f(unsigned short u) {
    return __builtin_bit_cast(float, ((unsigned int)u) << 16);
}
__device__ __forceinline__ float fexp2(float x) {
#if __has_builtin(__builtin_amdgcn_exp2f)
    return __builtin_amdgcn_exp2f(x);
#else
    return exp2f(x);
#endif
}
__device__ __forceinline__ float frcp(float x) {
#if __has_builtin(__builtin_amdgcn_rcpf)
    return __builtin_amdgcn_rcpf(x);
#else
    return 1.0f / x;
#endif
}
__device__ __forceinline__ float sigm(float x) {
    return frcp(1.0f + fexp2(-1.4426950408889634f * x));
}
__device__ __forceinline__ float tanh_f(float x) {
    return 1.0f - 2.0f * frcp(1.0f + fexp2(2.8853900817779268f * x));
}
__device__ __forceinline__ short8 ldfrag(const float* p, unsigned idx) {
    const float4* q = reinterpret_cast<const float4*>(p + idx);
    float4 a = q[0], b = q[1];
    short8 s;
    s[0] = (short)f2b(a.x); s[1] = (short)f2b(a.y);
    s[2] = (short)f2b(a.z); s[3] = (short)f2b(a.w);
    s[4] = (short)f2b(b.x); s[5] = (short)f2b(b.y);
    s[6] = (short)f2b(b.z); s[7] = (short)f2b(b.w);
    return s;
}

__global__ __launch_bounds__(NT, 1) void lstm2_fused(
    const float* __restrict__ hr,
    const float* __restrict__ glu,
    const float* __restrict__ wih0,
    const float* __restrict__ whh0,
    const float* __restrict__ bih0,
    const float* __restrict__ bhh0,
    const float* __restrict__ wih1,
    const float* __restrict__ whh1,
    const float* __restrict__ bih1,
    const float* __restrict__ bhh1,
    const float* __restrict__ w1,
    const float* __restrict__ b1,
    const float* __restrict__ w2,
    const float* __restrict__ b2,
    float* __restrict__ out)
{
    // hb[layer*2+parity][16 rows][HP]: layer0 rows {r, r+8 dup}; layer1 rows 8-15.
    __shared__ __align__(16) unsigned short hb[2 * 2 * 16 * HP];   // 17.4 KB
    __shared__ __align__(8)  float xin[(TT + 1) * 16];             // [t][8b][2] 32.8 KB
    __shared__ float bias0s[GG], bias1s[GG], wih0a[GG], wih0b[GG]; // 8 KB
    __shared__ float hid[BB][FFD];

    const int tid  = threadIdx.x;
    const int lane = tid & 63;
    const int wv   = tid >> 6;        // 0..7
    const int nrow = lane & 15;       // MFMA m (A) / n (B) index
    const int kg   = lane >> 4;       // quad 0..3
    const int b0   = blockIdx.x * BB;

    // ---- init LDS ----
    for (int i = tid; i < 2 * 2 * 16 * HP; i += NT) hb[i] = 0;
    for (int g = tid; g < GG; g += NT) {
        bias0s[g] = bih0[g] + bhh0[g];
        bias1s[g] = bih1[g] + bhh1[g];
        wih0a[g]  = wih0[2 * g];
        wih0b[g]  = wih0[2 * g + 1];
    }
    for (int i = tid; i < BB * TT; i += NT) {   // coalesced over t
        int b = i >> 9;
        int t = i & (TT - 1);
        unsigned gi = (unsigned)(b0 + b) * TT + t;
        xin[t * 16 + 2 * b]     = hr[gi];
        xin[t * 16 + 2 * b + 1] = glu[gi];
    }
    if (tid < 16) xin[TT * 16 + tid] = 0.f;

    // ---- weight fragments (B operand, R9-verified): gc = 128g + 16wv + nrow
    short8 W0f[4][4];   // whh0, K=128
    short8 W1f[4][8];   // wih1 (kt<4) / whh1 (kt>=4), K=256
#pragma unroll
    for (int g = 0; g < 4; g++) {
        unsigned gc = (unsigned)(128 * g + 16 * wv + nrow);
#pragma unroll
        for (int kt = 0; kt < 4; kt++) {
            unsigned off = gc * HH + kt * 32 + kg * 8;
            W0f[g][kt]     = ldfrag(whh0, off);
            W1f[g][kt]     = ldfrag(wih1, off);
            W1f[g][kt + 4] = ldfrag(whh1, off);
        }
    }
#pragma unroll
    for (int g = 0; g < 4; g++) {
#pragma unroll
        for (int kt = 0; kt < 4; kt++) { asm volatile("" : "+a"(W0f[g][kt])); }
#pragma unroll
        for (int kt = 0; kt < 8; kt++) { asm volatile("" : "+a"(W1f[g][kt])); }
    }

    // ---- per-lane roles & hoisted loop-invariant cell constants ----
    const bool is0  = (kg < 2);            // layer-0 cell lane?
    const int rbase = is0 ? 4 * kg : 4 * kg - 8;   // batch base 0/4
    const int j     = 16 * wv + nrow;      // hidden column
    const float* biasp = is0 ? bias0s : bias1s;
    const float bi = biasp[j], bf2 = biasp[j + 128],
                bg2 = biasp[j + 256], bo = biasp[j + 384];
    const float wai = wih0a[j], waf = wih0a[j + 128],
                wag = wih0a[j + 256], wao = wih0a[j + 384];
    const float wbi = wih0b[j], wbf = wih0b[j + 128],
                wbg = wih0b[j + 256], wbo = wih0b[j + 384];
    const unsigned lay  = is0 ? 0u : 2u;
    const unsigned wrow = is0 ? (unsigned)rbase : (unsigned)(8 + rbase);
    const unsigned dupo = is0 ? 8u * HP : 0u;
    float cst[4] = {0.f, 0.f, 0.f, 0.f};
    __syncthreads();

    // ---- recurrence: one barrier per iteration ----
    for (int it = 0; it <= TT; it++) {
        const int p = (it + 1) & 1;    // holds h0(it-1); h1(it-1) written here
        const int q = it & 1;          // holds h1(it-2); h0(it) written here

        const unsigned short* H0 = &hb[(0 + p) * 16 * HP + nrow * HP];
        const unsigned short* H1 = &hb[(2 + q) * 16 * HP + nrow * HP];

        f32x4 acc0[4], acc1[4];
        {   // kt = 0 peeled (C = 0)
            short8 a0 = *reinterpret_cast<const short8*>(H0 + kg * 8);
            f32x4 Z = {0.f, 0.f, 0.f, 0.f};
#pragma unroll
            for (int g = 0; g < 4; g++)
                acc0[g] = __builtin_amdgcn_mfma_f32_16x16x32_bf16(a0, W0f[g][0], Z, 0, 0, 0);
#pragma unroll
            for (int g = 0; g < 4; g++)
                acc1[g] = __builtin_amdgcn_mfma_f32_16x16x32_bf16(a0, W1f[g][0], Z, 0, 0, 0);
        }
#pragma unroll
        for (int kt = 1; kt < 4; kt++) {
            short8 a0 = *reinterpret_cast<const short8*>(H0 + kt * 32 + kg * 8);
#pragma unroll
            for (int g = 0; g < 4; g++)
                acc0[g] = __builtin_amdgcn_mfma_f32_16x16x32_bf16(a0, W0f[g][kt], acc0[g], 0, 0, 0);
#pragma unroll
            for (int g = 0; g < 4; g++)
                acc1[g] = __builtin_amdgcn_mfma_f32_16x16x32_bf16(a0, W1f[g][kt], acc1[g], 0, 0, 0);
        }
#pragma unroll
        for (int kt = 0; kt < 4; kt++) {
            short8 a1 = *reinterpret_cast<const short8*>(H1 + kt * 32 + kg * 8);
#pragma unroll
            for (int g = 0; g < 4; g++)
                acc1[g] = __builtin_amdgcn_mfma_f32_16x16x32_bf16(a1, W1f[g][kt + 4], acc1[g], 0, 0, 0);
        }

        // cell: lanes kg<2 use acc0 rows 0-7 (layer 0); kg>=2 use acc1 rows
        // 8-15 (layer 1). Branchless select; keep-trick bootstrap (R10-verified).
        const float keep = (it == 0 && !is0) ? 0.f : 1.f;
        unsigned short hv[4];
#pragma unroll
        for (int rr = 0; rr < 4; rr++) {
            float g0 = is0 ? acc0[0][rr] : acc1[0][rr];
            float g1 = is0 ? acc0[1][rr] : acc1[1][rr];
            float g2 = is0 ? acc0[2][rr] : acc1[2][rr];
            float g3 = is0 ? acc0[3][rr] : acc1[3][rr];
            int b = rbase + rr;
            float2 xv = *reinterpret_cast<const float2*>(&xin[it * 16 + 2 * b]);
            float xh = is0 ? xv.x : 0.f;
            float xg = is0 ? xv.y : 0.f;
            float p0 = g0 + bi  + xh * wai + xg * wbi;
            float p1 = g1 + bf2 + xh * waf + xg * wbf;
            float p2 = g2 + bg2 + xh * wag + xg * wbg;
            float p3 = g3 + bo  + xh * wao + xg * wbo;
            float ig = sigm(p0), fg = sigm(p1), gg = tanh_f(p2), og = sigm(p3);
            float c = (fg * cst[rr] + ig * gg) * keep;
            cst[rr] = c;
            hv[rr] = f2b(og * tanh_f(c));
        }
        const unsigned sel = is0 ? (unsigned)q : (unsigned)p;
        unsigned short* wp = &hb[(lay + sel) * 16 * HP + wrow * HP + j];
#pragma unroll
        for (int rr = 0; rr < 4; rr++) {
            wp[rr * HP]        = hv[rr];   // h0 row r / h1 row 8+r
            wp[rr * HP + dupo] = hv[rr];   // h0 dup row r+8 / h1 same-addr rewrite
        }
        __syncthreads();
    }

    // ---- head: h1(TT-1) = layer-1 parity-1 rows 8-15 ----
    {
        int r  = tid >> 6;      // 0..7
        int ff = tid & 63;
        const unsigned short* h1f = &hb[(2 + 1) * 16 * HP + (8 + r) * HP];
        float a2 = 0.f;
        for (int k = 0; k < HH; k++)
            a2 += b2f(h1f[k]) * w1[(unsigned)ff * HH + k];
        hid[r][ff] = fmaxf(a2 + b1[ff], 0.f);
    }
    __syncthreads();
    if (tid < 16) {
        int r = tid >> 1;
        int o = tid & 1;
        float a2 = b2[o];
        for (int k = 0; k < FFD; k++)
            a2 += hid[r][k] * w2[(unsigned)o * FFD + k];
        out[(b0 + r) * 2 + o] = a2;    // fp32 output
    }
}

extern "C" void kernel_launch(void* const* d_in, const int* in_sizes, int n_in,
                              void* d_out, int out_size, void* d_ws, size_t ws_size,
                              hipStream_t stream) {
    const float* hr   = (const float*)d_in[0];
    const float* glu  = (const float*)d_in[1];
    const float* wih0 = (const float*)d_in[2];
    const float* whh0 = (const float*)d_in[3];
    const float* bih0 = (const float*)d_in[4];
    const float* bhh0 = (const float*)d_in[5];
    const float* wih1 = (const float*)d_in[6];
    const float* whh1 = (const float*)d_in[7];
    const float* bih1 = (const float*)d_in[8];
    const float* bhh1 = (const float*)d_in[9];
    const float* w1   = (const float*)d_in[10];
    const float* b1   = (const float*)d_in[11];
    const float* w2   = (const float*)d_in[12];
    const float* b2   = (const float*)d_in[13];
    float* out = (float*)d_out;

    lstm2_fused<<<dim3(2048 / BB), dim3(NT), 0, stream>>>(
        hr, glu, wih0, whh0, bih0, bhh0, wih1, whh1, bih1, bhh1,
        w1, b1, w2, b2, out);
}